// Round 4
// baseline (317.343 us; speedup 1.0000x reference)
//
#include <hip/hip_runtime.h>

#define BATCH 64
#define SEQ   128
#define NLAB  32
#define NEGF  -3.0e38f
#define PA    132

// counted-waitcnt barrier: wait until <=K LDS ops outstanding, then s_barrier.
__device__ __forceinline__ void bar_k(int K) {
    switch (K) {
    case 0: asm volatile("s_waitcnt lgkmcnt(0)" ::: "memory"); break;
    case 1: asm volatile("s_waitcnt lgkmcnt(1)" ::: "memory"); break;
    case 2: asm volatile("s_waitcnt lgkmcnt(2)" ::: "memory"); break;
    default: asm volatile("s_waitcnt lgkmcnt(4)" ::: "memory"); break;
    }
    __builtin_amdgcn_s_barrier();
}

// cross-lane max via DPP (VALU pipe, not DS pipe)
__device__ __forceinline__ float qmax1(float v) {   // xor 1 within quad
    int t = __builtin_amdgcn_update_dpp(0, __float_as_int(v), 0xB1, 0xF, 0xF, true);
    return fmaxf(v, __int_as_float(t));
}
__device__ __forceinline__ float qmax2(float v) {   // xor 2 within quad
    int t = __builtin_amdgcn_update_dpp(0, __float_as_int(v), 0x4E, 0xF, 0xF, true);
    return fmaxf(v, __int_as_float(t));
}
__device__ __forceinline__ float rmax4(float v) {   // row_ror:4 (16-lane row)
    int t = __builtin_amdgcn_update_dpp(0, __float_as_int(v), 0x124, 0xF, 0xF, true);
    return fmaxf(v, __int_as_float(t));
}
__device__ __forceinline__ float rmax8(float v) {   // row_ror:8
    int t = __builtin_amdgcn_update_dpp(0, __float_as_int(v), 0x128, 0xF, 0xF, true);
    return fmaxf(v, __int_as_float(t));
}

// ---------------------------------------------------------------------------
// Kernel 1 (v5): pot + gold partials + inline len + out zeroing. (unchanged)
// ---------------------------------------------------------------------------
__global__ __launch_bounds__(256) void pot_gold_kernel(
    const float* __restrict__ logits, const int* __restrict__ labels,
    float* __restrict__ pot, float* __restrict__ gpart, float* __restrict__ out)
{
    const int tid = threadIdx.x;
    const int wave = tid >> 6, lane = tid & 63;
    __shared__ __align__(16) float LP[4 * 16 * 36];
    __shared__ float gred[4];
    __shared__ int s_len;
    float* W = LP + wave * (16 * 36);

    const int block_cell0 = blockIdx.x * 256;
    const int b = block_cell0 >> 14;
    const bool has_row0 = (blockIdx.x & 63) == 0;

    if (blockIdx.x == 0 && tid == 0) out[0] = 0.0f;

    if (has_row0 && tid < 64) {
        const size_t base = (size_t)b << 14;
        int cnt = (labels[base + tid] != -100) + (labels[base + 64 + tid] != -100);
        #pragma unroll
        for (int d = 32; d; d >>= 1) cnt += __shfl_down(cnt, d, 64);
        if (tid == 0) s_len = cnt;
    }
    __syncthreads();
    const int len = has_row0 ? s_len : -1;

    float gacc = 0.0f;
    const int wave_cell0 = block_cell0 + wave * 64;

    #pragma unroll
    for (int chunk = 0; chunk < 4; ++chunk) {
        const int c0 = wave_cell0 + chunk * 16;
        const float4* src = reinterpret_cast<const float4*>(logits) + ((size_t)c0 << 3);
        const float4 f0 = src[lane];
        const float4 f1 = src[lane + 64];
        const int lv = (lane < 16) ? labels[c0 + lane] : 0;

        {
            const int cA = lane >> 3, tA = lane & 7;
            *reinterpret_cast<float4*>(W + cA * 36 + tA * 4) = f0;
            const int q1 = lane + 64;
            const int cB = q1 >> 3, tB = q1 & 7;
            *reinterpret_cast<float4*>(W + cB * 36 + tB * 4) = f1;
        }
        const int c = lane >> 2, u = lane & 3;
        const float4 r0 = *reinterpret_cast<const float4*>(W + c * 36 + u * 8);
        const float4 r1 = *reinterpret_cast<const float4*>(W + c * 36 + u * 8 + 4);

        int lab = __shfl(lv, c, 64);
        if (lab < 0) lab = 0;
        const float l0 = __shfl(r0.x, c << 2, 64);

        const int cell = c0 + c;
        const int ci = (cell >> 7) & (SEQ - 1);
        const int cj = cell & (SEQ - 1);
        const bool special = (ci == 0) && (cj == len - 1);

        const float vv[8] = { r0.x, r0.y, r0.z, r0.w, r1.x, r1.y, r1.z, r1.w };
        float m = NEGF, g = 0.0f;
        #pragma unroll
        for (int e = 0; e < 8; ++e) {
            const int l = u * 8 + e;
            const float r = vv[e] - l0;
            const bool isg = (l == lab);
            g = isg ? r : g;
            float cand = r + (isg ? 0.0f : 1.0f);
            if (l == 0 && special) cand -= 1.0e9f;
            m = fmaxf(m, cand);
        }
        m = fmaxf(m, __shfl_xor(m, 1, 64));
        m = fmaxf(m, __shfl_xor(m, 2, 64));
        g += __shfl_xor(g, 1, 64);
        g += __shfl_xor(g, 2, 64);
        if (u == 0) {
            pot[cell] = m;
            gacc += g;
        }
    }

    #pragma unroll
    for (int d = 1; d < 64; d <<= 1) gacc += __shfl_xor(gacc, d, 64);
    if (lane == 0) gred[wave] = gacc;
    __syncthreads();
    if (tid == 0)
        gpart[blockIdx.x] = gred[0] + gred[1] + gred[2] + gred[3];
}

// ---------------------------------------------------------------------------
// Kernel 2 (v11): CKY with S-row-window bulk (phase A) + NEGF-poisoned tables.
// A[i][k] = score of span [i, i+k] (NEGF where not yet computed, incl pads,
// and a 4-float guard BEFORE A for col<0 reads). Bulk:
//   md[i][d] = max_{p in [i+1, i+W]} A[i][p-1-i] + A[p][(i+W+d)-p]
// For fixed p the 16 d-values are 16+3 consecutive floats of A-row p ->
// 6 aligned b128 serve 4 i-rows x 16 d. Uncomputed widths read NEGF (poison)
// so no masks. Lanes read consecutive p-rows (conflict-free). Reduction over
// the 16 p-lanes via DPP; leaders stage md to LDS for the phase-B thread map.
// pv now comes from global pot (L2-resident). Phase B / chunk 0 unchanged
// from v10 except md/pv sources.
// ---------------------------------------------------------------------------
__global__ __launch_bounds__(512, 1) void cky_kernel(
    const float* __restrict__ pot, const float* __restrict__ gpart,
    const int* __restrict__ labels, float* __restrict__ out)
{
    const int b = blockIdx.x;
    const int tid = threadIdx.x;
    const float* p = pot + (size_t)b * SEQ * SEQ;

    // [guard 4][A 128*132][Bt 128*132][stage 128*20]
    __shared__ __align__(16) float SH[4 + 2 * SEQ * PA + SEQ * 20];
    float* A = SH + 4;
    float* Bt = A + SEQ * PA;
    float* stage = Bt + SEQ * PA;
    __shared__ int s_len;
    __shared__ float s_gold;

    {   // poison everything to NEGF
        const float4 nf = { NEGF, NEGF, NEGF, NEGF };
        float4* sh4 = reinterpret_cast<float4*>(SH);
        const int NQ4 = (4 + 2 * SEQ * PA + SEQ * 20) / 4;
        for (int q = tid; q < NQ4; q += 512) sh4[q] = nf;
    }
    __syncthreads();

    if (tid < 128) {                                  // diagonal (width 0)
        const float v = p[tid * 129];
        A[tid * PA] = v;
        Bt[tid * PA + (SEQ - 1)] = v;
    } else if (tid < 192) {                           // len[b]
        const int lane = tid - 128;
        const size_t base = (size_t)b << 14;
        int cnt = (labels[base + lane] != -100) + (labels[base + 64 + lane] != -100);
        #pragma unroll
        for (int d = 32; d; d >>= 1) cnt += __shfl_down(cnt, d, 64);
        if (lane == 0) s_len = cnt;
    } else if (tid < 256) {                           // gold[b]
        const int lane = tid - 192;
        float g = gpart[b * 64 + lane];
        #pragma unroll
        for (int d = 32; d; d >>= 1) g += __shfl_down(g, d, 64);
        if (lane == 0) s_gold = g;
    }
    __syncthreads();

    const int i = tid >> 2, s = tid & 3;
    const int g  = tid >> 4;          // phase-A group (4 rows)
    const int i0 = g << 2;
    const int sp = tid & 15;          // phase-A p-lane
    const int rot = (4 - (sp & 3)) & 3;

    float alo[16], av[16];
    float boq[4], bfq[4];

#define C0_BODY(Sv)                                                           \
    if (s == (Sv)) {                                                          \
        _Pragma("unroll")                                                     \
        for (int e = 0; e < 4; ++e) {                                         \
            const int m = 4 * (Sv) + e;                                       \
            if (m < d) {                                                      \
                const float bv = ((Sv) == ((d - 1) >> 2))                     \
                    ? ((e == 0) ? fq.w : (e == 1) ? fq.z : (e == 2) ? fq.y : fq.x) \
                    : boq[e];                                                 \
                part = fmaxf(part, av[d - 1 - m] + bv);                       \
            }                                                                 \
        }                                                                     \
    }

#define CH_BODY(Sv)                                                           \
    if (s == (Sv)) {                                                          \
        _Pragma("unroll")                                                     \
        for (int e = 0; e < 4; ++e) {                                         \
            const int m = 4 * (Sv) + e;                                       \
            if (m < d) {                                                      \
                part = fmaxf(part, av[d - 1 - m] + boq[e]);                   \
                const float bv = ((Sv) == ((d - 1) >> 2))                     \
                    ? ((e == 0) ? fq.w : (e == 1) ? fq.z : (e == 2) ? fq.y : fq.x) \
                    : bfq[e];                                                 \
                part = fmaxf(part, alo[d - 1 - m] + bv);                      \
            }                                                                 \
        }                                                                     \
    }

    // ---------------- chunk 0: w = 1..15 ----------------
    float pvc[16];
    {
        const float* prow = p + i * 129;
        #pragma unroll
        for (int k = 0; k < 16; ++k) pvc[k] = prow[k];
    }
    av[0] = pvc[0];

    {   // initial prefetch for step d=1
        const int jp = (i + 1 < SEQ) ? (i + 1) : (SEQ - 1);
        const float4 bv = *reinterpret_cast<const float4*>(&Bt[jp * PA + 124 - 4 * s]);
        boq[0] = bv.w; boq[1] = bv.z; boq[2] = bv.y; boq[3] = bv.x;
    }

    #pragma unroll
    for (int d = 1; d < 16; ++d) {
        const int j = i + d;
        const int jr = (j < SEQ) ? j : SEQ - 1;
        const float4 fq = *reinterpret_cast<const float4*>(&Bt[jr * PA + 124 - 4 * ((d - 1) >> 2)]);
        float part = NEGF;
        C0_BODY(0)
        C0_BODY(1)
        C0_BODY(2)
        C0_BODY(3)
        part = qmax2(qmax1(part));
        const float val = part + pvc[d];
        av[d] = val;
        if (j < SEQ && s < 2) {
            float* pw = (s == 0) ? &A[i * PA + d] : &Bt[j * PA + (SEQ - 1 - d)];
            *pw = val;
        }
        __builtin_amdgcn_sched_barrier(0);
        if (d < 15) {
            const int jp = (j + 1 < SEQ) ? (j + 1) : (SEQ - 1);
            const float4 bv = *reinterpret_cast<const float4*>(&Bt[jp * PA + 124 - 4 * s]);
            boq[0] = bv.w; boq[1] = bv.z; boq[2] = bv.y; boq[3] = bv.x;
            bar_k(1);
        } else {
            bar_k(0);
        }
    }
    #pragma unroll
    for (int k = 0; k < 16; ++k) alo[k] = av[k];

    // ---------------- chunks W = 16..112 ----------------
    for (int W = 16; W < SEQ; W += 16) {
        // pv for phase B from global pot (L2-resident; latency hidden by phase A)
        float pvn[16];
        {
            const float* prow = p + i * 129 + W;
            #pragma unroll
            for (int k = 0; k < 16; ++k) pvn[k] = prow[k];
        }

        // ---- phase A: S-row-window bulk ----
        if (i0 + W <= 127) {
            float md2[4][16];
            #pragma unroll
            for (int r = 0; r < 4; ++r)
                #pragma unroll
                for (int d = 0; d < 16; ++d) md2[r][d] = NEGF;

            const int NIT = (W + 64) >> 6;
            for (int n = 0; n < NIT; ++n) {
                #pragma unroll
                for (int ep = 0; ep < 4; ++ep) {
                    const int pbase = (n << 6) + (ep << 4);
                    if (pbase <= W) {                 // wave-uniform skip
                        const int pp = pbase + sp;    // p - i0
                        const bool act = (pp <= W);
                        // A-side: own-row left scores A[i0+r][pp-1-r]
                        float avv[4];
                        #pragma unroll
                        for (int r = 0; r < 4; ++r) {
                            const float v = A[(i0 + r) * PA + (pp - 1 - r)];
                            avv[r] = act ? v : NEGF;
                        }
                        // B-side: 24-float window of A-row p covering cols j-p
                        const int prow_ = (i0 + pp <= 127) ? (i0 + pp) : 127;
                        int al = (W - pp) & ~3; if (al < 0) al = 0;
                        const float* wp = &A[prow_ * PA + al];
                        float w24[24];
                        #pragma unroll
                        for (int t = 0; t < 6; ++t) {
                            const float4 v = *reinterpret_cast<const float4*>(wp + 4 * t);
                            w24[4*t] = v.x; w24[4*t+1] = v.y; w24[4*t+2] = v.z; w24[4*t+3] = v.w;
                        }
                        // rotate window by lane-constant rot so pos = r+d
                        float wr[19];
                        {
                            float t1[21];
                            #pragma unroll
                            for (int k = 0; k < 21; ++k) t1[k] = (rot & 1) ? w24[k + 1] : w24[k];
                            #pragma unroll
                            for (int k = 0; k < 19; ++k) wr[k] = (rot & 2) ? t1[k + 2] : t1[k];
                        }
                        #pragma unroll
                        for (int r = 0; r < 4; ++r)
                            #pragma unroll
                            for (int d = 0; d < 16; ++d)
                                md2[r][d] = fmaxf(md2[r][d], avv[r] + wr[r + d]);
                    }
                }
            }
            // reduce across the 16 p-lanes (DPP, VALU pipe)
            #pragma unroll
            for (int r = 0; r < 4; ++r)
                #pragma unroll
                for (int d = 0; d < 16; ++d) {
                    float v = md2[r][d];
                    v = qmax2(qmax1(v));
                    v = rmax4(rmax8(v));
                    md2[r][d] = v;
                }
            if (sp == 0) {
                #pragma unroll
                for (int r = 0; r < 4; ++r)
                    #pragma unroll
                    for (int t = 0; t < 4; ++t) {
                        float4 v;
                        v.x = md2[r][4*t]; v.y = md2[r][4*t+1];
                        v.z = md2[r][4*t+2]; v.w = md2[r][4*t+3];
                        *reinterpret_cast<float4*>(&stage[(i0 + r) * 20 + 4 * t]) = v;
                    }
            }
        }
        __syncthreads();

        float mdv[16];
        #pragma unroll
        for (int t = 0; t < 4; ++t) {
            const float4 v = *reinterpret_cast<const float4*>(&stage[i * 20 + 4 * t]);
            mdv[4*t] = v.x; mdv[4*t+1] = v.y; mdv[4*t+2] = v.z; mdv[4*t+3] = v.w;
        }

        // ---- phase B (v10 structure) ----
        {   // step d = 0
            const int j = i + W;
            const float val = mdv[0] + pvn[0];
            av[0] = val;
            if (j < SEQ && s < 2) {
                float* pw = (s == 0) ? &A[i * PA + W] : &Bt[j * PA + (SEQ - 1 - W)];
                *pw = val;
            }
            __builtin_amdgcn_sched_barrier(0);
            const int jp = (j + 1 < SEQ) ? (j + 1) : (SEQ - 1);
            const float4 bv = *reinterpret_cast<const float4*>(&Bt[jp * PA + 124 - 4 * s]);
            const float4 fv = *reinterpret_cast<const float4*>(&Bt[jp * PA + 124 - W - 4 * s]);
            boq[0] = bv.w; boq[1] = bv.z; boq[2] = bv.y; boq[3] = bv.x;
            bfq[0] = fv.w; bfq[1] = fv.z; bfq[2] = fv.y; bfq[3] = fv.x;
            bar_k(2);
        }
        #pragma unroll
        for (int d = 1; d < 16; ++d) {
            const int w = W + d;
            const int j = i + w;
            const int jr = (j < SEQ) ? j : SEQ - 1;
            const float4 fq = *reinterpret_cast<const float4*>(
                &Bt[jr * PA + 124 - W - 4 * ((d - 1) >> 2)]);
            float part = NEGF;
            CH_BODY(0)
            CH_BODY(1)
            CH_BODY(2)
            CH_BODY(3)
            part = qmax2(qmax1(part));
            const float val = fmaxf(part, mdv[d]) + pvn[d];
            av[d] = val;
            if (j < SEQ && s < 2) {
                float* pw = (s == 0) ? &A[i * PA + w] : &Bt[j * PA + (SEQ - 1 - w)];
                *pw = val;
            }
            __builtin_amdgcn_sched_barrier(0);
            if (d < 15) {
                const int jp = (j + 1 < SEQ) ? (j + 1) : (SEQ - 1);
                const float4 bv = *reinterpret_cast<const float4*>(&Bt[jp * PA + 124 - 4 * s]);
                const float4 fv = *reinterpret_cast<const float4*>(&Bt[jp * PA + 124 - W - 4 * s]);
                boq[0] = bv.w; boq[1] = bv.z; boq[2] = bv.y; boq[3] = bv.x;
                bfq[0] = fv.w; bfq[1] = fv.z; bfq[2] = fv.y; bfq[3] = fv.x;
                bar_k(2);
            } else {
                bar_k(0);
            }
        }
    }

    if (tid == 0) {
        const int len = s_len;
        const float pred = A[len - 1];        // A[0][len-1]
        const float margin = fmaxf(pred - s_gold, 0.0f);
        atomicAdd(out, margin * (1.0f / (float)BATCH));
    }
#undef C0_BODY
#undef CH_BODY
}

extern "C" void kernel_launch(void* const* d_in, const int* in_sizes, int n_in,
                              void* d_out, int out_size, void* d_ws, size_t ws_size,
                              hipStream_t stream) {
    const float* logits = (const float*)d_in[0];
    const int* labels = (const int*)d_in[1];
    float* out = (float*)d_out;

    float* pot = (float*)d_ws;                          // B*N*N floats = 4 MB
    float* gpart = pot + (size_t)BATCH * SEQ * SEQ;     // 4096 floats

    pot_gold_kernel<<<BATCH * SEQ * SEQ / 256, 256, 0, stream>>>(
        logits, labels, pot, gpart, out);
    cky_kernel<<<BATCH, 512, 0, stream>>>(pot, gpart, labels, out);
}

// Round 5
// 253.543 us; speedup vs baseline: 1.2516x; 1.2516x over previous
//
#include <hip/hip_runtime.h>

#define BATCH 64
#define SEQ   128
#define NLAB  32
#define NEGF  -3.0e38f
// PA = 136 (row pitch, floats). 136 ≡ 8 (mod 32 banks): phase-A lanes
// (i,s) reading Bt[(i+W+d)*PA + c + 4s] land on bank 8((i+d)%4)+4s →
// 16 distinct banks over the 16 (i%4,s) combos → 4-way conflict max.
// (PA=132 ≡ 4 mod 32 gave bank 4((i+s)+d): 8 groups → 8-way, ~2.9x cost.)
#define PA    136

// counted-waitcnt barrier: wait until <=K LDS ops outstanding, then s_barrier.
// DS ops retire in-order, so writes issued BEFORE the last K reads are complete.
__device__ __forceinline__ void bar_k(int K) {
    switch (K) {
    case 0: asm volatile("s_waitcnt lgkmcnt(0)" ::: "memory"); break;
    case 1: asm volatile("s_waitcnt lgkmcnt(1)" ::: "memory"); break;
    case 2: asm volatile("s_waitcnt lgkmcnt(2)" ::: "memory"); break;
    case 3: asm volatile("s_waitcnt lgkmcnt(3)" ::: "memory"); break;
    case 4: asm volatile("s_waitcnt lgkmcnt(4)" ::: "memory"); break;
    case 5: asm volatile("s_waitcnt lgkmcnt(5)" ::: "memory"); break;
    case 6: asm volatile("s_waitcnt lgkmcnt(6)" ::: "memory"); break;
    default: asm volatile("s_waitcnt lgkmcnt(7)" ::: "memory"); break;
    }
    __builtin_amdgcn_s_barrier();
}

// 4-lane max reduction via DPP quad_perm (VALU pipe, not DS pipe).
__device__ __forceinline__ float qmax1(float v) {   // xor 1: perm {1,0,3,2}
    int t = __builtin_amdgcn_update_dpp(0, __float_as_int(v), 0xB1, 0xF, 0xF, true);
    return fmaxf(v, __int_as_float(t));
}
__device__ __forceinline__ float qmax2(float v) {   // xor 2: perm {2,3,0,1}
    int t = __builtin_amdgcn_update_dpp(0, __float_as_int(v), 0x4E, 0xF, 0xF, true);
    return fmaxf(v, __int_as_float(t));
}

// ---------------------------------------------------------------------------
// Kernel 1 (v5): pot + gold partials + inline len + out zeroing.
// ---------------------------------------------------------------------------
__global__ __launch_bounds__(256) void pot_gold_kernel(
    const float* __restrict__ logits, const int* __restrict__ labels,
    float* __restrict__ pot, float* __restrict__ gpart, float* __restrict__ out)
{
    const int tid = threadIdx.x;
    const int wave = tid >> 6, lane = tid & 63;
    __shared__ __align__(16) float LP[4 * 16 * 36];   // 9216 B
    __shared__ float gred[4];
    __shared__ int s_len;
    float* W = LP + wave * (16 * 36);

    const int block_cell0 = blockIdx.x * 256;
    const int b = block_cell0 >> 14;
    const bool has_row0 = (blockIdx.x & 63) == 0;

    if (blockIdx.x == 0 && tid == 0) out[0] = 0.0f;   // replaces hipMemsetAsync

    if (has_row0 && tid < 64) {
        const size_t base = (size_t)b << 14;
        int cnt = (labels[base + tid] != -100) + (labels[base + 64 + tid] != -100);
        #pragma unroll
        for (int d = 32; d; d >>= 1) cnt += __shfl_down(cnt, d, 64);
        if (tid == 0) s_len = cnt;
    }
    __syncthreads();
    const int len = has_row0 ? s_len : -1;

    float gacc = 0.0f;
    const int wave_cell0 = block_cell0 + wave * 64;

    #pragma unroll
    for (int chunk = 0; chunk < 4; ++chunk) {
        const int c0 = wave_cell0 + chunk * 16;
        const float4* src = reinterpret_cast<const float4*>(logits) + ((size_t)c0 << 3);
        const float4 f0 = src[lane];
        const float4 f1 = src[lane + 64];
        const int lv = (lane < 16) ? labels[c0 + lane] : 0;

        {
            const int cA = lane >> 3, tA = lane & 7;
            *reinterpret_cast<float4*>(W + cA * 36 + tA * 4) = f0;
            const int q1 = lane + 64;
            const int cB = q1 >> 3, tB = q1 & 7;
            *reinterpret_cast<float4*>(W + cB * 36 + tB * 4) = f1;
        }
        const int c = lane >> 2, u = lane & 3;
        const float4 r0 = *reinterpret_cast<const float4*>(W + c * 36 + u * 8);
        const float4 r1 = *reinterpret_cast<const float4*>(W + c * 36 + u * 8 + 4);

        int lab = __shfl(lv, c, 64);
        if (lab < 0) lab = 0;
        const float l0 = __shfl(r0.x, c << 2, 64);

        const int cell = c0 + c;
        const int ci = (cell >> 7) & (SEQ - 1);
        const int cj = cell & (SEQ - 1);
        const bool special = (ci == 0) && (cj == len - 1);

        const float vv[8] = { r0.x, r0.y, r0.z, r0.w, r1.x, r1.y, r1.z, r1.w };
        float m = NEGF, g = 0.0f;
        #pragma unroll
        for (int e = 0; e < 8; ++e) {
            const int l = u * 8 + e;
            const float r = vv[e] - l0;
            const bool isg = (l == lab);
            g = isg ? r : g;
            float cand = r + (isg ? 0.0f : 1.0f);
            if (l == 0 && special) cand -= 1.0e9f;
            m = fmaxf(m, cand);
        }
        m = fmaxf(m, __shfl_xor(m, 1, 64));
        m = fmaxf(m, __shfl_xor(m, 2, 64));
        g += __shfl_xor(g, 1, 64);
        g += __shfl_xor(g, 2, 64);
        if (u == 0) {
            pot[cell] = m;
            gacc += g;
        }
    }

    #pragma unroll
    for (int d = 1; d < 64; d <<= 1) gacc += __shfl_xor(gacc, d, 64);
    if (lane == 0) gred[wave] = gacc;
    __syncthreads();
    if (tid == 0)
        gpart[blockIdx.x] = gred[0] + gred[1] + gred[2] + gred[3];
}

// ---------------------------------------------------------------------------
// Kernel 2 (v10b): chunked two-phase CKY (v10 structure, PA=136 anti-conflict).
// Edge-term loads split across the 4 s-lanes of each row (lane s owns
// m in [4s,4s+4)); per step the wave issues only:
//   1 uniform "fresh" quad read, 1 bo-prefetch quad, 1 bf-prefetch quad
//   (in flight across the counted barrier), 1 fused A/Bt write.
// Partial maxes combined across s via DPP quad_perm (VALU, not DS pipe).
// ---------------------------------------------------------------------------
__global__ __launch_bounds__(512, 1) void cky_kernel(
    const float* __restrict__ pot, const float* __restrict__ gpart,
    const int* __restrict__ labels, float* __restrict__ out)
{
    const int b = blockIdx.x;
    const int tid = threadIdx.x;
    const float* p = pot + (size_t)b * SEQ * SEQ;

    __shared__ __align__(16) float A[SEQ * PA];       // 69632 B
    __shared__ __align__(16) float Bt[SEQ * PA];      // 69632 B
    __shared__ int s_len;
    __shared__ float s_gold;

    if (tid < 64) {                                   // len[b]
        const size_t base = (size_t)b << 14;
        int cnt = (labels[base + tid] != -100) + (labels[base + 64 + tid] != -100);
        #pragma unroll
        for (int d = 32; d; d >>= 1) cnt += __shfl_down(cnt, d, 64);
        if (tid == 0) s_len = cnt;
    } else if (tid < 128) {                           // gold[b] from partials
        float g = gpart[b * 64 + (tid - 64)];
        #pragma unroll
        for (int d = 32; d; d >>= 1) g += __shfl_down(g, d, 64);
        if (tid == 64) s_gold = g;
    }

    {   // scatter pot into both tables; preload all 8 quads first (ILP)
        const float4* p4 = reinterpret_cast<const float4*>(p);
        float4 vb[8];
        #pragma unroll
        for (int t = 0; t < 8; ++t) vb[t] = p4[tid + 512 * t];
        #pragma unroll
        for (int t = 0; t < 8; ++t) {
            const int qi = tid + 512 * t;
            const int i0 = qi >> 5;
            const int j0 = (qi & 31) << 2;
            const float vv[4] = { vb[t].x, vb[t].y, vb[t].z, vb[t].w };
            #pragma unroll
            for (int c2 = 0; c2 < 4; ++c2) {
                const int j = j0 + c2;
                if (j >= i0) {
                    A[i0 * PA + (j - i0)] = vv[c2];
                    Bt[j * PA + (SEQ - 1 - (j - i0))] = vv[c2];
                }
            }
        }
    }
    __syncthreads();

    const int i = tid >> 2, s = tid & 3;
    float alo[16], av[16], pv[16];
    float boq[4], bfq[4];

    // lane-s edge body, chunk 0 (bo terms only; fresh-quad lane uses fq)
#define C0_BODY(Sv)                                                           \
    if (s == (Sv)) {                                                          \
        _Pragma("unroll")                                                     \
        for (int e = 0; e < 4; ++e) {                                         \
            const int m = 4 * (Sv) + e;                                       \
            if (m < d) {                                                      \
                const float bv = ((Sv) == ((d - 1) >> 2))                     \
                    ? ((e == 0) ? fq.w : (e == 1) ? fq.z : (e == 2) ? fq.y : fq.x) \
                    : boq[e];                                                 \
                part = fmaxf(part, av[d - 1 - m] + bv);                       \
            }                                                                 \
        }                                                                     \
    }

    // lane-s edge body, chunks >= 16 (bo via prefetch, bf fresh-or-prefetch)
#define CH_BODY(Sv)                                                           \
    if (s == (Sv)) {                                                          \
        _Pragma("unroll")                                                     \
        for (int e = 0; e < 4; ++e) {                                         \
            const int m = 4 * (Sv) + e;                                       \
            if (m < d) {                                                      \
                part = fmaxf(part, av[d - 1 - m] + boq[e]);                   \
                const float bv = ((Sv) == ((d - 1) >> 2))                     \
                    ? ((e == 0) ? fq.w : (e == 1) ? fq.z : (e == 2) ? fq.y : fq.x) \
                    : bfq[e];                                                 \
                part = fmaxf(part, alo[d - 1 - m] + bv);                      \
            }                                                                 \
        }                                                                     \
    }

    // ---------------- chunk 0: w = 1..15 ----------------
    #pragma unroll
    for (int t = 0; t < 4; ++t) {
        const float4 v = *reinterpret_cast<const float4*>(&A[i * PA + 4 * t]);
        pv[4*t] = v.x; pv[4*t+1] = v.y; pv[4*t+2] = v.z; pv[4*t+3] = v.w;
    }
    av[0] = pv[0];

    {   // initial prefetch for step d=1 (row i+1, quad t=s, widths 4s..4s+3)
        const int jp = (i + 1 < SEQ) ? (i + 1) : (SEQ - 1);
        const float4 bv = *reinterpret_cast<const float4*>(&Bt[jp * PA + 124 - 4 * s]);
        boq[0] = bv.w; boq[1] = bv.z; boq[2] = bv.y; boq[3] = bv.x;
    }

    #pragma unroll
    for (int d = 1; d < 16; ++d) {
        const int j = i + d;
        const int jr = (j < SEQ) ? j : SEQ - 1;
        // uniform fresh quad: t = (d-1)>>2 of row j (contains width d-1)
        const float4 fq = *reinterpret_cast<const float4*>(&Bt[jr * PA + 124 - 4 * ((d - 1) >> 2)]);
        float part = NEGF;
        C0_BODY(0)
        C0_BODY(1)
        C0_BODY(2)
        C0_BODY(3)
        part = qmax2(qmax1(part));
        const float val = part + pv[d];
        av[d] = val;
        if (j < SEQ && s < 2) {
            float* pw = (s == 0) ? &A[i * PA + d] : &Bt[j * PA + (SEQ - 1 - d)];
            *pw = val;
        }
        __builtin_amdgcn_sched_barrier(0);
        if (d < 15) {   // prefetch own quad t=s of row j+1 for step d+1
            const int jp = (j + 1 < SEQ) ? (j + 1) : (SEQ - 1);
            const float4 bv = *reinterpret_cast<const float4*>(&Bt[jp * PA + 124 - 4 * s]);
            boq[0] = bv.w; boq[1] = bv.z; boq[2] = bv.y; boq[3] = bv.x;
            bar_k(1);
        } else {
            bar_k(0);
        }
    }
    #pragma unroll
    for (int k = 0; k < 16; ++k) alo[k] = av[k];

    // ---------------- chunks W = 16..112 ----------------
    for (int W = 16; W < SEQ; W += 16) {
        // pv = A[i][W..W+15] (pot values, stable until this chunk's writes)
        #pragma unroll
        for (int t = 0; t < 4; ++t) {
            const float4 v = *reinterpret_cast<const float4*>(&A[i * PA + W + 4 * t]);
            pv[4*t] = v.x; pv[4*t+1] = v.y; pv[4*t+2] = v.z; pv[4*t+3] = v.w;
        }
        float md[16];
        #pragma unroll
        for (int d = 0; d < 16; ++d) md[d] = NEGF;

        // ---- phase A: bulk k in [d, W-1], all data pre-chunk ----
        {   // first quad (k0 = 4s <= 12): mask k >= d
            const int k0 = s << 2;
            const float4 a = *reinterpret_cast<const float4*>(&A[i * PA + k0]);
            const float aa[4] = { a.x, a.y, a.z, a.w };
            #pragma unroll
            for (int d = 0; d < 16; ++d) {
                const int j = i + W + d;
                if (j < SEQ) {
                    const float* bp = &Bt[j * PA + (SEQ - W - d) + k0];
                    float b0, b1, b2, b3;
                    if ((d & 3) == 0) {
                        const float4 v = *reinterpret_cast<const float4*>(bp);
                        b0 = v.x; b1 = v.y; b2 = v.z; b3 = v.w;
                    } else if ((d & 3) == 2) {
                        const float2 v0 = *reinterpret_cast<const float2*>(bp);
                        const float2 v1 = *reinterpret_cast<const float2*>(bp + 2);
                        b0 = v0.x; b1 = v0.y; b2 = v1.x; b3 = v1.y;
                    } else {
                        b0 = bp[0];
                        const float2 v = *reinterpret_cast<const float2*>(bp + 1);
                        b1 = v.x; b2 = v.y; b3 = bp[3];
                    }
                    const float a0 = (k0 + 0 >= d) ? aa[0] : NEGF;
                    const float a1 = (k0 + 1 >= d) ? aa[1] : NEGF;
                    const float a2 = (k0 + 2 >= d) ? aa[2] : NEGF;
                    const float a3 = (k0 + 3 >= d) ? aa[3] : NEGF;
                    md[d] = fmaxf(md[d], fmaxf(fmaxf(a0 + b0, a1 + b1),
                                               fmaxf(a2 + b2, a3 + b3)));
                }
            }
        }
        for (int q = s + 4; q < (W >> 2); q += 4) {   // k0 >= 16 > d: no masks
            const int k0 = q << 2;
            const float4 a = *reinterpret_cast<const float4*>(&A[i * PA + k0]);
            #pragma unroll
            for (int d = 0; d < 16; ++d) {
                const int j = i + W + d;
                if (j < SEQ) {
                    const float* bp = &Bt[j * PA + (SEQ - W - d) + k0];
                    float b0, b1, b2, b3;
                    if ((d & 3) == 0) {
                        const float4 v = *reinterpret_cast<const float4*>(bp);
                        b0 = v.x; b1 = v.y; b2 = v.z; b3 = v.w;
                    } else if ((d & 3) == 2) {
                        const float2 v0 = *reinterpret_cast<const float2*>(bp);
                        const float2 v1 = *reinterpret_cast<const float2*>(bp + 2);
                        b0 = v0.x; b1 = v0.y; b2 = v1.x; b3 = v1.y;
                    } else {
                        b0 = bp[0];
                        const float2 v = *reinterpret_cast<const float2*>(bp + 1);
                        b1 = v.x; b2 = v.y; b3 = bp[3];
                    }
                    md[d] = fmaxf(md[d], fmaxf(fmaxf(a.x + b0, a.y + b1),
                                               fmaxf(a.z + b2, a.w + b3)));
                }
            }
        }
        #pragma unroll
        for (int d = 0; d < 16; ++d) {    // 4-lane butterfly via DPP (VALU)
            md[d] = qmax2(qmax1(md[d]));
        }

        // ---- phase B ----
        {   // step d = 0: no edge terms; prefetch both quads for step 1
            const int j = i + W;
            const float val = md[0] + pv[0];
            av[0] = val;
            if (j < SEQ && s < 2) {
                float* pw = (s == 0) ? &A[i * PA + W] : &Bt[j * PA + (SEQ - 1 - W)];
                *pw = val;
            }
            __builtin_amdgcn_sched_barrier(0);
            const int jp = (j + 1 < SEQ) ? (j + 1) : (SEQ - 1);
            const float4 bv = *reinterpret_cast<const float4*>(&Bt[jp * PA + 124 - 4 * s]);
            const float4 fv = *reinterpret_cast<const float4*>(&Bt[jp * PA + 124 - W - 4 * s]);
            boq[0] = bv.w; boq[1] = bv.z; boq[2] = bv.y; boq[3] = bv.x;
            bfq[0] = fv.w; bfq[1] = fv.z; bfq[2] = fv.y; bfq[3] = fv.x;
            bar_k(2);
        }
        #pragma unroll
        for (int d = 1; d < 16; ++d) {
            const int w = W + d;
            const int j = i + w;
            const int jr = (j < SEQ) ? j : SEQ - 1;
            // uniform fresh bf quad: t=(d-1)>>2 of row j (contains width w-1)
            const float4 fq = *reinterpret_cast<const float4*>(
                &Bt[jr * PA + 124 - W - 4 * ((d - 1) >> 2)]);
            float part = NEGF;
            CH_BODY(0)
            CH_BODY(1)
            CH_BODY(2)
            CH_BODY(3)
            part = qmax2(qmax1(part));
            const float val = fmaxf(part, md[d]) + pv[d];
            av[d] = val;
            if (j < SEQ && s < 2) {
                float* pw = (s == 0) ? &A[i * PA + w] : &Bt[j * PA + (SEQ - 1 - w)];
                *pw = val;
            }
            __builtin_amdgcn_sched_barrier(0);
            if (d < 15) {   // prefetch own bo+bf quads of row j+1 for step d+1
                const int jp = (j + 1 < SEQ) ? (j + 1) : (SEQ - 1);
                const float4 bv = *reinterpret_cast<const float4*>(&Bt[jp * PA + 124 - 4 * s]);
                const float4 fv = *reinterpret_cast<const float4*>(&Bt[jp * PA + 124 - W - 4 * s]);
                boq[0] = bv.w; boq[1] = bv.z; boq[2] = bv.y; boq[3] = bv.x;
                bfq[0] = fv.w; bfq[1] = fv.z; bfq[2] = fv.y; bfq[3] = fv.x;
                bar_k(2);
            } else {
                bar_k(0);
            }
        }
    }

    if (tid == 0) {
        const int len = s_len;
        const float pred = A[len - 1];        // A[0][len-1]
        const float margin = fmaxf(pred - s_gold, 0.0f);
        atomicAdd(out, margin * (1.0f / (float)BATCH));
    }
#undef C0_BODY
#undef CH_BODY
}

extern "C" void kernel_launch(void* const* d_in, const int* in_sizes, int n_in,
                              void* d_out, int out_size, void* d_ws, size_t ws_size,
                              hipStream_t stream) {
    const float* logits = (const float*)d_in[0];
    const int* labels = (const int*)d_in[1];
    float* out = (float*)d_out;

    float* pot = (float*)d_ws;                          // B*N*N floats = 4 MB
    float* gpart = pot + (size_t)BATCH * SEQ * SEQ;     // 4096 floats

    pot_gold_kernel<<<BATCH * SEQ * SEQ / 256, 256, 0, stream>>>(
        logits, labels, pot, gpart, out);
    cky_kernel<<<BATCH, 512, 0, stream>>>(pot, gpart, labels, out);
}